// Round 10
// baseline (180.156 us; speedup 1.0000x reference)
//
#include <hip/hip_runtime.h>
#include <hip/hip_bf16.h>

#define ATTN_N 8192
#define ATTN_D 128
#define TKEYS 64                      // keys per LDS tile
#define NTILES (ATTN_N / TKEYS)       // 128
#define TILE_ELEMS (TKEYS * ATTN_D)   // 8192 bf16 = 16 KB
#define QROWS 128                     // queries per block
#define NSPLIT 8                      // split-K ways
#define KTPB (NTILES / NSPLIT)        // 16 key tiles per block

typedef __bf16 bf16_t;
typedef bf16_t bf16x2 __attribute__((ext_vector_type(2)));
typedef bf16_t bf16x4 __attribute__((ext_vector_type(4)));
typedef bf16_t bf16x8 __attribute__((ext_vector_type(8)));
typedef float f32x4 __attribute__((ext_vector_type(4)));

#if __has_builtin(__builtin_amdgcn_exp2f)
#define EXP2(x) __builtin_amdgcn_exp2f(x)
#else
#define EXP2(x) __expf((x) * 0.6931471805599453f)
#endif

// Async global->LDS DMA, 16 B per lane; lane-linear on both sides (m104).
__device__ __forceinline__ void dma16(const bf16_t* g, bf16_t* l) {
  __builtin_amdgcn_global_load_lds(
      (const __attribute__((address_space(1))) void*)g,
      (__attribute__((address_space(3))) void*)l, 16, 0, 0);
}

// ---------------------------------------------------------------------------
// Prep (unchanged from R9): Q -> bf16 linear (scaled log2(e)/sqrt(128));
// K -> 64-key tile image (chunk j at j^(r&15)); V -> transposed 64-key tile
// image (key positions pairwise interleaved per 32-window, chunks ^(d&7)).
// ---------------------------------------------------------------------------
__global__ void prep_kernel(const float* __restrict__ q,
                            const float* __restrict__ k,
                            const float* __restrict__ v,
                            bf16_t* __restrict__ qb,
                            bf16_t* __restrict__ kswz,
                            bf16_t* __restrict__ vtswz) {
  __shared__ bf16_t tile[64][72];
  const int bk = blockIdx.x;      // 64-key tile index, 0..127
  const int bd = blockIdx.y;      // 64-d half, 0..1
  const int t = threadIdx.x;      // 0..255
  const float sc = 0.12751744f;   // log2(e) / sqrt(128)

  const int row_l = t >> 2;             // 0..63 (key within tile)
  const int key = bk * 64 + row_l;

#pragma unroll
  for (int u = 0; u < 2; ++u) {
    const int j = bd * 8 + (t & 3) * 2 + u;   // d-chunk 0..15
    const float4* qs = (const float4*)(q + (size_t)key * ATTN_D + j * 8);
    const float4* ks = (const float4*)(k + (size_t)key * ATTN_D + j * 8);
    float4 a0 = qs[0], a1 = qs[1];
    float4 b0 = ks[0], b1 = ks[1];
    bf16x8 qo, ko;
    qo[0] = (bf16_t)(a0.x * sc); qo[1] = (bf16_t)(a0.y * sc);
    qo[2] = (bf16_t)(a0.z * sc); qo[3] = (bf16_t)(a0.w * sc);
    qo[4] = (bf16_t)(a1.x * sc); qo[5] = (bf16_t)(a1.y * sc);
    qo[6] = (bf16_t)(a1.z * sc); qo[7] = (bf16_t)(a1.w * sc);
    ko[0] = (bf16_t)b0.x; ko[1] = (bf16_t)b0.y;
    ko[2] = (bf16_t)b0.z; ko[3] = (bf16_t)b0.w;
    ko[4] = (bf16_t)b1.x; ko[5] = (bf16_t)b1.y;
    ko[6] = (bf16_t)b1.z; ko[7] = (bf16_t)b1.w;
    *(bf16x8*)(qb + (size_t)key * ATTN_D + j * 8) = qo;
    *(bf16x8*)(kswz + (size_t)bk * TILE_ELEMS + row_l * ATTN_D +
               (j ^ (row_l & 15)) * 8) = ko;
  }

  {
    const float* src = v + (size_t)key * ATTN_D + bd * 64 + (t & 3) * 16;
#pragma unroll
    for (int u = 0; u < 4; ++u) {
      float4 a = ((const float4*)src)[u];
      tile[row_l][(t & 3) * 16 + u * 4 + 0] = (bf16_t)a.x;
      tile[row_l][(t & 3) * 16 + u * 4 + 1] = (bf16_t)a.y;
      tile[row_l][(t & 3) * 16 + u * 4 + 2] = (bf16_t)a.z;
      tile[row_l][(t & 3) * 16 + u * 4 + 3] = (bf16_t)a.w;
    }
  }
  __syncthreads();
  {
    const int d_l = t >> 2;            // 0..63
    const int d = bd * 64 + d_l;       // V-tile row
#pragma unroll
    for (int u = 0; u < 2; ++u) {
      const int j = (t & 3) * 2 + u;   // key-chunk position 0..7
      bf16x8 o;
#pragma unroll
      for (int i = 0; i < 8; ++i) {
        const int p = 8 * j + i;       // global position 0..63
        const int lp = p & 31;
        const int key_t = (p >> 5) * 32 + (lp >> 1) + 16 * (lp & 1);
        o[i] = tile[key_t][d_l];
      }
      *(bf16x8*)(vtswz + (size_t)bk * TILE_ELEMS + d * TKEYS +
                 ((j ^ (d & 7)) * 8)) = o;
    }
  }
}

// ---------------------------------------------------------------------------
// Flash attention, 128 queries/block x 8-way split-K, 2 blocks/CU.
//   grid = 512 blocks (qg = blk>>3, kh = blk&7) x 512 threads (8 waves).
//   kh == XCD (blk%8) -> each XCD L2 holds only its 256 KB K-eighth +
//   256 KB V-eighth.
//   Wave (rowG = w&3, keyH = w>>2): 32 rows x 32-key window as 2 m-subtiles
//   -> every K/V fragment read feeds 2 MFMAs (R6's LDS-per-MAC efficiency)
//   AND 16 waves/CU (R9's TLP). LDS exactly 80 KB/block:
//     KV dbuf 64 KB + Ps 16 KB (stride 32, XOR-chunk swizzle; cmb aliased
//     into Ps; fp32 Ob[128][128] aliased onto dead KV in epilogue).
//   exp2-only softmax (pure-sum denominator), DMA double-buffer, one
//   barrier/iter. Unnormalized bf16 partial O + fp32 partial L out
//   (nontemporal); merge kernel sums 8 parts and normalizes.
// MFMA layouts (mfma_f32_16x16x32_bf16, verified gfx950):
//   A: m = lane&15, k = (lane>>4)*8 + j
//   B: n = lane&15, k = (lane>>4)*8 + j
//   C/D: col = lane&15, row = (lane>>4)*4 + reg
// Ps swizzle: row stride 32 elems (4 chunks of 8); chunk c stored at
//   c ^ (row&3). Writes: pair {p0,p1} at dword pos col -> chunk col>>2.
//   A-reads: lane wants [m=col][chunk=quad] -> (quad^(col&3))*8. Uniform
//   bank spread for both.
// ---------------------------------------------------------------------------
__global__ __launch_bounds__(512, 4) void flash_attn_kernel(
    const bf16_t* __restrict__ qb, const bf16_t* __restrict__ kswz,
    const bf16_t* __restrict__ vtswz, bf16_t* __restrict__ partO,
    float* __restrict__ partL) {
  __shared__ __align__(16) bf16_t KV[2][2][TILE_ELEMS];  // 64 KB
  __shared__ __align__(16) bf16_t Ps[8][32][32];         // 16 KB
  // Epilogue aliases (all uses are after the K-loop's final barrier):
  float* Ob = (float*)&KV[0][0][0];           // [128][128] fp32 = 64 KB
  float (*cmb)[32] = (float(*)[32])&Ps[0][0][0];  // [8][32] = 1 KB

  const int t = threadIdx.x;
  const int w = t >> 6;
  const int lane = t & 63;
  const int quad = lane >> 4;
  const int col = lane & 15;
  const int rowG = w & 3;          // 32-row group
  const int keyH = w >> 2;         // 32-key window
  const int blk = blockIdx.x;
  const int qg = blk >> 3;
  const int kh = blk & 7;
  const int q0 = qg * QROWS;
  const int ktbase = kh * KTPB;
  const int stg = qg & (KTPB - 1);   // intra-XCD phase decorrelation

  // Swizzled LDS element offsets for K/V fragment reads (as R9).
  int offK[4][2], offV[8];
#pragma unroll
  for (int c = 0; c < 4; ++c)
#pragma unroll
    for (int cs = 0; cs < 2; ++cs)
      offK[c][cs] = (keyH * 32 + cs * 16 + col) * ATTN_D +
                    (((c * 4 + quad) ^ col) * 8);
#pragma unroll
  for (int ds = 0; ds < 8; ++ds)
    offV[ds] = (ds * 16 + col) * TKEYS + (((keyH * 4 + quad) ^ (col & 7)) * 8);

  // Q fragments: 2 m-subtiles x 4 k-chunks, registers for the whole kernel.
  bf16x8 aq[2][4];
#pragma unroll
  for (int mi = 0; mi < 2; ++mi) {
    const int row = q0 + rowG * 32 + mi * 16 + col;
#pragma unroll
    for (int c = 0; c < 4; ++c)
      aq[mi][c] = *(const bf16x8*)(qb + (size_t)row * ATTN_D + c * 32 + quad * 8);
  }

  f32x4 oacc[2][8];
#pragma unroll
  for (int mi = 0; mi < 2; ++mi)
#pragma unroll
    for (int i = 0; i < 8; ++i) oacc[mi][i] = (f32x4){0.f, 0.f, 0.f, 0.f};
  float l_part[2][4] = {{0.f, 0.f, 0.f, 0.f}, {0.f, 0.f, 0.f, 0.f}};

  // Prologue DMA: first tile into buf 0 (512 thr x 2 chunks per operand).
  {
    const int kt = ktbase + stg;
    const bf16_t* kg = kswz + (size_t)kt * TILE_ELEMS + t * 8;
    const bf16_t* vg = vtswz + (size_t)kt * TILE_ELEMS + t * 8;
#pragma unroll
    for (int u = 0; u < 2; ++u) {
      dma16(kg + u * 4096, &KV[0][0][t * 8 + u * 4096]);
      dma16(vg + u * 4096, &KV[0][1][t * 8 + u * 4096]);
    }
  }
  __syncthreads();

  for (int it = 0; it < KTPB; ++it) {
    const int buf = it & 1;
    if (it + 1 < KTPB) {
      const int nt = ktbase + ((stg + it + 1) & (KTPB - 1));
      const bf16_t* kg = kswz + (size_t)nt * TILE_ELEMS + t * 8;
      const bf16_t* vg = vtswz + (size_t)nt * TILE_ELEMS + t * 8;
      bf16_t* kl = &KV[buf ^ 1][0][t * 8];
      bf16_t* vl = &KV[buf ^ 1][1][t * 8];
#pragma unroll
      for (int u = 0; u < 2; ++u) {
        dma16(kg + u * 4096, kl + u * 4096);
        dma16(vg + u * 4096, vl + u * 4096);
      }
    }
    const bf16_t* Kb = KV[buf][0];
    const bf16_t* Vb = KV[buf][1];

    // --- S = Q K^T: 2 m-subtiles x 2 n-subtiles; K frags shared across mi.
    f32x4 s[2][2];
#pragma unroll
    for (int mi = 0; mi < 2; ++mi)
#pragma unroll
      for (int ni = 0; ni < 2; ++ni) s[mi][ni] = (f32x4){0.f, 0.f, 0.f, 0.f};
#pragma unroll
    for (int c = 0; c < 4; ++c) {
      bf16x8 b0 = *(const bf16x8*)(Kb + offK[c][0]);
      bf16x8 b1 = *(const bf16x8*)(Kb + offK[c][1]);
      s[0][0] = __builtin_amdgcn_mfma_f32_16x16x32_bf16(aq[0][c], b0, s[0][0], 0, 0, 0);
      s[1][0] = __builtin_amdgcn_mfma_f32_16x16x32_bf16(aq[1][c], b0, s[1][0], 0, 0, 0);
      s[0][1] = __builtin_amdgcn_mfma_f32_16x16x32_bf16(aq[0][c], b1, s[0][1], 0, 0, 0);
      s[1][1] = __builtin_amdgcn_mfma_f32_16x16x32_bf16(aq[1][c], b1, s[1][1], 0, 0, 0);
    }

    // --- p = 2^s; lane-local denominator; swizzled packed pair-store
    //     (pair {key col, key col+16} at dword pos col, chunk-XOR'd by row&3).
#pragma unroll
    for (int mi = 0; mi < 2; ++mi)
#pragma unroll
      for (int r = 0; r < 4; ++r) {
        float p0 = EXP2(s[mi][0][r]);
        float p1 = EXP2(s[mi][1][r]);
        l_part[mi][r] += p0 + p1;
        const int eoff = (((col >> 2) ^ r) * 8) + (col & 3) * 2;
        *(bf16x2*)&Ps[w][mi * 16 + quad * 4 + r][eoff] =
            (bf16x2){(bf16_t)p0, (bf16_t)p1};
      }

    // --- O += P V: V frags shared across the 2 m-subtiles.
    bf16x8 ap0 = *(const bf16x8*)&Ps[w][col][(quad ^ (col & 3)) * 8];
    bf16x8 ap1 = *(const bf16x8*)&Ps[w][16 + col][(quad ^ (col & 3)) * 8];
#pragma unroll
    for (int ds = 0; ds < 8; ++ds) {
      bf16x8 bv = *(const bf16x8*)(Vb + offV[ds]);
      oacc[0][ds] = __builtin_amdgcn_mfma_f32_16x16x32_bf16(ap0, bv, oacc[0][ds], 0, 0, 0);
      oacc[1][ds] = __builtin_amdgcn_mfma_f32_16x16x32_bf16(ap1, bv, oacc[1][ds], 0, 0, 0);
    }
    __syncthreads();  // drains prefetch vmcnt + protects buffer swap
  }

  // --- epilogue: denominator reduce -> cmb (aliased on Ps; all Ps reads
  //     completed before the loop's final barrier).
#pragma unroll
  for (int mi = 0; mi < 2; ++mi)
#pragma unroll
    for (int r = 0; r < 4; ++r) {
      float v = l_part[mi][r];
#pragma unroll
      for (int off = 1; off < 16; off <<= 1)
        v += __shfl_xor(v, off, 64);
      if (col == 0) cmb[w][mi * 16 + quad * 4 + r] = v;
    }
  __syncthreads();
  if (t < QROWS) {
    partL[(size_t)blk * QROWS + t] = cmb[t >> 5][t & 31] + cmb[(t >> 5) + 4][t & 31];
  }

  // --- 2-way keyH merge of O into Ob (aliased on dead KV; stride 128).
  if (keyH == 0) {
#pragma unroll
    for (int mi = 0; mi < 2; ++mi)
#pragma unroll
      for (int ds = 0; ds < 8; ++ds)
#pragma unroll
        for (int r = 0; r < 4; ++r) {
          const int row = rowG * 32 + mi * 16 + quad * 4 + r;
          Ob[row * 128 + ds * 16 + col] = oacc[mi][ds][r];
        }
  }
  __syncthreads();
  if (keyH == 1) {
#pragma unroll
    for (int mi = 0; mi < 2; ++mi)
#pragma unroll
      for (int ds = 0; ds < 8; ++ds)
#pragma unroll
        for (int r = 0; r < 4; ++r) {
          const int row = rowG * 32 + mi * 16 + quad * 4 + r;
          Ob[row * 128 + ds * 16 + col] += oacc[mi][ds][r];
        }
  }
  __syncthreads();

  // --- cooperative nontemporal bf16 write of the 128x128 partial O.
  {
    bf16_t* dst = partO + (size_t)blk * (QROWS * ATTN_D);
    const int row = t >> 2;
    const int c0 = (t & 3) * 32;
#pragma unroll
    for (int u = 0; u < 4; ++u) {
      bf16x8 o;
#pragma unroll
      for (int i = 0; i < 8; ++i)
        o[i] = (bf16_t)Ob[row * 128 + c0 + u * 8 + i];
      __builtin_nontemporal_store(o, (bf16x8*)(dst + row * ATTN_D + c0 + u * 8));
    }
  }
}

// ---------------------------------------------------------------------------
// Merge: out[row] = sum_j O_j[row] / sum_j L_j[row], j = 8 split-K parts.
//   1024 blocks x 256 threads, one float4 (4 elems) per thread.
// ---------------------------------------------------------------------------
__global__ void merge_kernel(const bf16_t* __restrict__ partO,
                             const float* __restrict__ partL,
                             float* __restrict__ out) {
  const int idx = blockIdx.x * blockDim.x + threadIdx.x;  // 4-elem index
  const int row = idx >> 5;          // 32 quads per 128-elem row
  const int gi = row >> 7;           // query group (128 rows)
  const int rl = row & 127;
  const int eoff = rl * ATTN_D + (idx & 31) * 4;
  float L = 0.f;
  float o0 = 0.f, o1 = 0.f, o2 = 0.f, o3 = 0.f;
#pragma unroll
  for (int j = 0; j < NSPLIT; ++j) {
    const int blk = gi * NSPLIT + j;
    const bf16x4 a = __builtin_nontemporal_load(
        (const bf16x4*)(partO + (size_t)blk * (QROWS * ATTN_D) + eoff));
    L += partL[(size_t)blk * QROWS + rl];
    o0 += (float)a[0]; o1 += (float)a[1]; o2 += (float)a[2]; o3 += (float)a[3];
  }
  const float invL = 1.0f / L;
  f32x4 o = (f32x4){o0 * invL, o1 * invL, o2 * invL, o3 * invL};
  *((f32x4*)out + idx) = o;
}

// ---------------------------------------------------------------------------
extern "C" void kernel_launch(void* const* d_in, const int* in_sizes, int n_in,
                              void* d_out, int out_size, void* d_ws, size_t ws_size,
                              hipStream_t stream) {
  const float* q = (const float*)d_in[0];
  const float* k = (const float*)d_in[1];
  const float* v = (const float*)d_in[2];
  float* out = (float*)d_out;

  // Workspace: qb|kswz|vtswz (bf16, 2 MB each) | partO bf16 16 MB | partL 256 KB.
  bf16_t* qb = (bf16_t*)d_ws;
  bf16_t* kswz = qb + (size_t)ATTN_N * ATTN_D;
  bf16_t* vtswz = kswz + (size_t)ATTN_N * ATTN_D;
  bf16_t* partO = vtswz + (size_t)ATTN_N * ATTN_D;
  float* partL = (float*)(partO + (size_t)512 * QROWS * ATTN_D);

  prep_kernel<<<dim3(ATTN_N / 64, 2), 256, 0, stream>>>(q, k, v, qb, kswz, vtswz);
  flash_attn_kernel<<<512, 512, 0, stream>>>(qb, kswz, vtswz, partO, partL);
  merge_kernel<<<(ATTN_N * ATTN_D / 4) / 256, 256, 0, stream>>>(partO, partL, out);
}